// Round 4
// baseline (961.871 us; speedup 1.0000x reference)
//
#include <hip/hip_runtime.h>
#include <math.h>

#define N_NODES 50000
#define N_EDGES 400000
#define HD 32
#define N_ET 8
#define CAP 64   // ELL capacity; Poisson(8) max degree ~30, P(>=64) ~ 1e-40

__device__ inline void fma4(float4& a, float s, const float4 w) {
    a.x = fmaf(s, w.x, a.x);
    a.y = fmaf(s, w.y, a.y);
    a.z = fmaf(s, w.z, a.z);
    a.w = fmaf(s, w.w, a.w);
}
__device__ inline void add4(float4& a, const float4 v) {
    a.x += v.x; a.y += v.y; a.z += v.z; a.w += v.w;
}

// Build ELL adjacency keyed by dst: payload[d][k] = pid*N_NODES + src
__global__ __launch_bounds__(256) void k_count(
    const int* __restrict__ src, const int* __restrict__ dst,
    const int* __restrict__ pid, int* __restrict__ deg,
    int* __restrict__ payload)
{
    int e = blockIdx.x * blockDim.x + threadIdx.x;
    if (e >= N_EDGES) return;
    int d = dst[e];
    int pos = atomicAdd(&deg[d], 1);
    if (pos < CAP) payload[d * CAP + pos] = pid[e] * N_NODES + src[e];
}

// Transform: Y[t][n] = x[n] @ W_t.  One edge-type per block (blockIdx.y) so the
// weight pointer is wave-uniform -> s_load; one node per thread.
__global__ __launch_bounds__(256) void k_transform(
    const float* __restrict__ xin, const float* __restrict__ param,
    float* __restrict__ Y)
{
    int n = blockIdx.x * blockDim.x + threadIdx.x;
    if (n >= N_NODES) return;
    const int t = blockIdx.y;
    const size_t base = (size_t)n * HD;
    const float* W = param + t * (HD * HD);

    float x[HD];
    #pragma unroll
    for (int q = 0; q < 8; ++q) {
        float4 v = *(const float4*)(xin + base + q * 4);
        x[q * 4 + 0] = v.x; x[q * 4 + 1] = v.y;
        x[q * 4 + 2] = v.z; x[q * 4 + 3] = v.w;
    }

    float4 acc[8];
    #pragma unroll
    for (int q = 0; q < 8; ++q) acc[q] = make_float4(0.f, 0.f, 0.f, 0.f);
    #pragma unroll
    for (int i = 0; i < HD; ++i) {
        float xi = x[i];
        #pragma unroll
        for (int q = 0; q < 8; ++q)
            fma4(acc[q], xi, *(const float4*)(W + i * HD + q * 4));
    }
    float* yo = Y + (size_t)t * N_NODES * HD + base;
    #pragma unroll
    for (int q = 0; q < 8; ++q) *(float4*)(yo + q * 4) = acc[q];
}

// Gather + combine: xout[n] = (xin[n] + sum_{e in in(n)} Y[pid_e][src_e]) * 0.5
// 8 lanes per node; lane sl owns a 16B slice. 4 edges in flight (MLP=4).
__global__ __launch_bounds__(256) void k_gather(
    const int* __restrict__ deg, const int* __restrict__ payload,
    const float* __restrict__ Y, const float* __restrict__ xin,
    float* __restrict__ xout)
{
    int tid = blockIdx.x * blockDim.x + threadIdx.x;
    int node = tid >> 3, sl = tid & 7;
    if (node >= N_NODES) return;
    int d = deg[node];
    if (d > CAP) d = CAP;
    const int* pl = payload + node * CAP;

    float4 a0 = make_float4(0.f,0.f,0.f,0.f), a1 = a0, a2 = a0, a3 = a0;
    int k = 0;
    for (; k + 4 <= d; k += 4) {
        int4 c = *(const int4*)(pl + k);              // 16B aligned (k%4==0)
        float4 v0 = *(const float4*)(Y + (size_t)c.x * HD + sl * 4);
        float4 v1 = *(const float4*)(Y + (size_t)c.y * HD + sl * 4);
        float4 v2 = *(const float4*)(Y + (size_t)c.z * HD + sl * 4);
        float4 v3 = *(const float4*)(Y + (size_t)c.w * HD + sl * 4);
        add4(a0, v0); add4(a1, v1); add4(a2, v2); add4(a3, v3);
    }
    for (; k < d; ++k) {
        int c = pl[k];
        add4(a0, *(const float4*)(Y + (size_t)c * HD + sl * 4));
    }
    add4(a0, a1); add4(a2, a3); add4(a0, a2);

    const size_t off = (size_t)node * HD + sl * 4;
    float4 x = *(const float4*)(xin + off);
    x.x = (x.x + a0.x) * 0.5f;
    x.y = (x.y + a0.y) * 0.5f;
    x.z = (x.z + a0.z) * 0.5f;
    x.w = (x.w + a0.w) * 0.5f;
    *(float4*)(xout + off) = x;
}

// Final: L2-normalize ; MLP 32->64 tanh ->64 tanh ->1 ; sigmoid.
// 4 lanes per node: lane q owns hidden cols [16q,16q+16). Layer-2 input slices
// exchanged via width-4 shuffles. Weights via vector loads: within a wave all
// node-groups share the same weight addresses (only q varies) -> 1 line/instr.
__global__ __launch_bounds__(256) void k_final(
    const float* __restrict__ cur,
    const float* __restrict__ w1, const float* __restrict__ b1,
    const float* __restrict__ w2, const float* __restrict__ b2,
    const float* __restrict__ w3, const float* __restrict__ b3,
    float* __restrict__ out)
{
    int gt = blockIdx.x * blockDim.x + threadIdx.x;
    int n = gt >> 2, q = gt & 3;
    if (n >= N_NODES) return;
    const size_t base = (size_t)n * HD;

    float x[HD];
    float ss = 0.f;
    #pragma unroll
    for (int r = 0; r < 8; ++r) {
        float4 v = *(const float4*)(cur + base + r * 4);
        ss += v.x * v.x + v.y * v.y + v.z * v.z + v.w * v.w;
        x[r * 4 + 0] = v.x; x[r * 4 + 1] = v.y;
        x[r * 4 + 2] = v.z; x[r * 4 + 3] = v.w;
    }
    float rn = 1.0f / fmaxf(sqrtf(ss), 1e-12f);
    #pragma unroll
    for (int i = 0; i < HD; ++i) x[i] *= rn;

    // layer 1: cols [16q, 16q+16)
    float4 h[4];
    #pragma unroll
    for (int j = 0; j < 4; ++j) h[j] = *(const float4*)(b1 + q * 16 + j * 4);
    #pragma unroll
    for (int i = 0; i < HD; ++i) {
        #pragma unroll
        for (int j = 0; j < 4; ++j)
            fma4(h[j], x[i], *(const float4*)(w1 + i * 64 + q * 16 + j * 4));
    }
    float t1[16];
    #pragma unroll
    for (int j = 0; j < 4; ++j) {
        t1[j * 4 + 0] = tanhf(h[j].x); t1[j * 4 + 1] = tanhf(h[j].y);
        t1[j * 4 + 2] = tanhf(h[j].z); t1[j * 4 + 3] = tanhf(h[j].w);
    }

    // layer 2: ring over the 4 input slices
    float4 h2[4];
    #pragma unroll
    for (int j = 0; j < 4; ++j) h2[j] = *(const float4*)(b2 + q * 16 + j * 4);
    #pragma unroll
    for (int s = 0; s < 4; ++s) {
        #pragma unroll
        for (int k = 0; k < 16; ++k) {
            float m = __shfl(t1[k], s, 4);
            #pragma unroll
            for (int j = 0; j < 4; ++j)
                fma4(h2[j], m, *(const float4*)(w2 + (s * 16 + k) * 64 + q * 16 + j * 4));
        }
    }

    // layer 3: partial dot over own 16 cols, reduce across the 4 lanes
    float p = 0.f;
    #pragma unroll
    for (int j = 0; j < 4; ++j) {
        float4 w = *(const float4*)(w3 + q * 16 + j * 4);
        p = fmaf(tanhf(h2[j].x), w.x, p);
        p = fmaf(tanhf(h2[j].y), w.y, p);
        p = fmaf(tanhf(h2[j].z), w.z, p);
        p = fmaf(tanhf(h2[j].w), w.w, p);
    }
    p += __shfl_xor(p, 1, 4);
    p += __shfl_xor(p, 2, 4);
    if (q == 0) out[n] = 1.0f / (1.0f + expf(-(p + b3[0])));
}

extern "C" void kernel_launch(void* const* d_in, const int* in_sizes, int n_in,
                              void* d_out, int out_size, void* d_ws, size_t ws_size,
                              hipStream_t stream) {
    const float* feature = (const float*)d_in[0];
    const float* param   = (const float*)d_in[1];
    const float* w1      = (const float*)d_in[2];
    const float* b1      = (const float*)d_in[3];
    const float* w2      = (const float*)d_in[4];
    const float* b2      = (const float*)d_in[5];
    const float* w3      = (const float*)d_in[6];
    const float* b3      = (const float*)d_in[7];
    const int*   src     = (const int*)d_in[8];
    const int*   dst     = (const int*)d_in[9];
    const int*   pid     = (const int*)d_in[10];
    float* out = (float*)d_out;

    const size_t Y_BYTES   = (size_t)N_ET * N_NODES * HD * sizeof(float);   // 51.2 MB
    const size_t NH_BYTES  = (size_t)N_NODES * HD * sizeof(float);          // 6.4 MB
    const size_t DEG_BYTES = (size_t)N_NODES * sizeof(int);                 // 0.2 MB
    char* p = (char*)d_ws;
    float* Y       = (float*)p;            p += Y_BYTES;
    float* cur     = (float*)p;            p += NH_BYTES;
    int*   deg     = (int*)p;              p += DEG_BYTES;
    int*   payload = (int*)p;              // 50K * 64 * 4B = 12.8 MB

    const int TB = 256;
    const int gT = (N_NODES + TB - 1) / TB;          // 196
    const int gE = (N_EDGES + TB - 1) / TB;
    const int gG = (N_NODES * 8 + TB - 1) / TB;      // 1563
    const int gF = (N_NODES * 4 + TB - 1) / TB;      // 782
    dim3 gridT(gT, N_ET);                            // 1568 blocks, t uniform per block

    // Build dst-keyed ELL adjacency (int atomics only, once per launch)
    hipMemsetAsync(deg, 0, DEG_BYTES, stream);
    k_count<<<gE, TB, 0, stream>>>(src, dst, pid, deg, payload);

    // layer 1
    k_transform<<<gridT, TB, 0, stream>>>(feature, param, Y);
    k_gather<<<gG, TB, 0, stream>>>(deg, payload, Y, feature, cur);
    // layer 2
    k_transform<<<gridT, TB, 0, stream>>>(cur, param, Y);
    k_gather<<<gG, TB, 0, stream>>>(deg, payload, Y, cur, cur);
    // layer 3
    k_transform<<<gridT, TB, 0, stream>>>(cur, param, Y);
    k_gather<<<gG, TB, 0, stream>>>(deg, payload, Y, cur, cur);
    // normalize + MLP + sigmoid
    k_final<<<gF, TB, 0, stream>>>(cur, w1, b1, w2, b2, w3, b3, out);
}

// Round 5
// 329.882 us; speedup vs baseline: 2.9158x; 2.9158x over previous
//
#include <hip/hip_runtime.h>
#include <math.h>

#define N_NODES 50000
#define N_EDGES 400000
#define HD 32
#define N_ET 8
#define CAP 64   // ELL capacity; Poisson(8) max degree ~30, P(>=64) ~ 1e-40

__device__ inline void fma4(float4& a, float s, const float4 w) {
    a.x = fmaf(s, w.x, a.x);
    a.y = fmaf(s, w.y, a.y);
    a.z = fmaf(s, w.z, a.z);
    a.w = fmaf(s, w.w, a.w);
}
__device__ inline void add4(float4& a, const float4 v) {
    a.x += v.x; a.y += v.y; a.z += v.z; a.w += v.w;
}

// Build ELL adjacency keyed by dst: payload[d][k] = pid*N_NODES + src
__global__ __launch_bounds__(256) void k_count(
    const int* __restrict__ src, const int* __restrict__ dst,
    const int* __restrict__ pid, int* __restrict__ deg,
    int* __restrict__ payload)
{
    int e = blockIdx.x * blockDim.x + threadIdx.x;
    if (e >= N_EDGES) return;
    int d = dst[e];
    int pos = atomicAdd(&deg[d], 1);
    if (pos < CAP) payload[d * CAP + pos] = pid[e] * N_NODES + src[e];
}

// Transform: Y[t][n] = x[n] @ W_t.  One edge-type per block (blockIdx.y) so the
// weight pointer is wave-uniform -> s_load; one node per thread.
__global__ __launch_bounds__(256) void k_transform(
    const float* __restrict__ xin, const float* __restrict__ param,
    float* __restrict__ Y)
{
    int n = blockIdx.x * blockDim.x + threadIdx.x;
    if (n >= N_NODES) return;
    const int t = blockIdx.y;
    const size_t base = (size_t)n * HD;
    const float* W = param + t * (HD * HD);

    float x[HD];
    #pragma unroll
    for (int q = 0; q < 8; ++q) {
        float4 v = *(const float4*)(xin + base + q * 4);
        x[q * 4 + 0] = v.x; x[q * 4 + 1] = v.y;
        x[q * 4 + 2] = v.z; x[q * 4 + 3] = v.w;
    }

    float4 acc[8];
    #pragma unroll
    for (int q = 0; q < 8; ++q) acc[q] = make_float4(0.f, 0.f, 0.f, 0.f);
    #pragma unroll
    for (int i = 0; i < HD; ++i) {
        float xi = x[i];
        #pragma unroll
        for (int q = 0; q < 8; ++q)
            fma4(acc[q], xi, *(const float4*)(W + i * HD + q * 4));
    }
    float* yo = Y + (size_t)t * N_NODES * HD + base;
    #pragma unroll
    for (int q = 0; q < 8; ++q) *(float4*)(yo + q * 4) = acc[q];
}

// Gather + combine: xout[n] = (xin[n] + sum_{e in in(n)} Y[pid_e][src_e]) * 0.5
// 8 lanes per node; lane sl owns a 16B slice. 4 edges in flight (MLP=4).
__global__ __launch_bounds__(256) void k_gather(
    const int* __restrict__ deg, const int* __restrict__ payload,
    const float* __restrict__ Y, const float* __restrict__ xin,
    float* __restrict__ xout)
{
    int tid = blockIdx.x * blockDim.x + threadIdx.x;
    int node = tid >> 3, sl = tid & 7;
    if (node >= N_NODES) return;
    int d = deg[node];
    if (d > CAP) d = CAP;
    const int* pl = payload + node * CAP;

    float4 a0 = make_float4(0.f,0.f,0.f,0.f), a1 = a0, a2 = a0, a3 = a0;
    int k = 0;
    for (; k + 4 <= d; k += 4) {
        int4 c = *(const int4*)(pl + k);              // 16B aligned (k%4==0)
        float4 v0 = *(const float4*)(Y + (size_t)c.x * HD + sl * 4);
        float4 v1 = *(const float4*)(Y + (size_t)c.y * HD + sl * 4);
        float4 v2 = *(const float4*)(Y + (size_t)c.z * HD + sl * 4);
        float4 v3 = *(const float4*)(Y + (size_t)c.w * HD + sl * 4);
        add4(a0, v0); add4(a1, v1); add4(a2, v2); add4(a3, v3);
    }
    for (; k < d; ++k) {
        int c = pl[k];
        add4(a0, *(const float4*)(Y + (size_t)c * HD + sl * 4));
    }
    add4(a0, a1); add4(a2, a3); add4(a0, a2);

    const size_t off = (size_t)node * HD + sl * 4;
    float4 x = *(const float4*)(xin + off);
    x.x = (x.x + a0.x) * 0.5f;
    x.y = (x.y + a0.y) * 0.5f;
    x.z = (x.z + a0.z) * 0.5f;
    x.w = (x.w + a0.w) * 0.5f;
    *(float4*)(xout + off) = x;
}

// Final: L2-normalize ; MLP 32->64 tanh ->64 tanh ->1 ; sigmoid.
// 4 lanes/node; lane q owns hidden cols [16q,16q+16). Layer-1 outputs exchanged
// through an LDS row (stride 65 -> (nl+i)%32 banks, conflict-free broadcast).
// Layer-2 loop stays ROLLED to keep live registers small (R4 spilled at 256 VGPR).
__global__ __launch_bounds__(256) void k_final(
    const float* __restrict__ cur,
    const float* __restrict__ w1, const float* __restrict__ b1,
    const float* __restrict__ w2, const float* __restrict__ b2,
    const float* __restrict__ w3, const float* __restrict__ b3,
    float* __restrict__ out)
{
    __shared__ float t1s[64 * 65];               // 64 nodes/block, stride 65
    int gt = blockIdx.x * blockDim.x + threadIdx.x;
    int node = gt >> 2, q = gt & 3;
    int nl = threadIdx.x >> 2;                   // node-local 0..63
    int n = node < N_NODES ? node : N_NODES - 1; // clamp: no early return (barrier)
    const size_t base = (size_t)n * HD;

    float x[HD];
    float ss = 0.f;
    #pragma unroll
    for (int r = 0; r < 8; ++r) {
        float4 v = *(const float4*)(cur + base + r * 4);
        ss += v.x * v.x + v.y * v.y + v.z * v.z + v.w * v.w;
        x[r * 4 + 0] = v.x; x[r * 4 + 1] = v.y;
        x[r * 4 + 2] = v.z; x[r * 4 + 3] = v.w;
    }
    float rn = 1.0f / fmaxf(sqrtf(ss), 1e-12f);

    // layer 1: cols [16q, 16q+16); accumulators only 4 float4
    float4 h[4];
    #pragma unroll
    for (int j = 0; j < 4; ++j) h[j] = *(const float4*)(b1 + q * 16 + j * 4);
    #pragma unroll
    for (int i = 0; i < HD; ++i) {
        float xi = x[i] * rn;
        #pragma unroll
        for (int j = 0; j < 4; ++j)
            fma4(h[j], xi, *(const float4*)(w1 + i * 64 + q * 16 + j * 4));
    }
    float* row = t1s + nl * 65;
    #pragma unroll
    for (int j = 0; j < 4; ++j) {
        row[q * 16 + j * 4 + 0] = tanhf(h[j].x);
        row[q * 16 + j * 4 + 1] = tanhf(h[j].y);
        row[q * 16 + j * 4 + 2] = tanhf(h[j].z);
        row[q * 16 + j * 4 + 3] = tanhf(h[j].w);
    }
    __syncthreads();

    // layer 2: rolled 64-iter loop; per iter: 1 ds_read (4-lane broadcast),
    // 4 coalesced float4 weight loads, 16 FMA. Live set stays ~h2 only.
    float4 h2[4];
    #pragma unroll
    for (int j = 0; j < 4; ++j) h2[j] = *(const float4*)(b2 + q * 16 + j * 4);
    #pragma unroll 2
    for (int i = 0; i < 64; ++i) {
        float m = row[i];
        const float* wr = w2 + i * 64 + q * 16;
        #pragma unroll
        for (int j = 0; j < 4; ++j)
            fma4(h2[j], m, *(const float4*)(wr + j * 4));
    }

    // layer 3: partial dot over own 16 cols, reduce across the 4 lanes
    float p = 0.f;
    #pragma unroll
    for (int j = 0; j < 4; ++j) {
        float4 w = *(const float4*)(w3 + q * 16 + j * 4);
        p = fmaf(tanhf(h2[j].x), w.x, p);
        p = fmaf(tanhf(h2[j].y), w.y, p);
        p = fmaf(tanhf(h2[j].z), w.z, p);
        p = fmaf(tanhf(h2[j].w), w.w, p);
    }
    p += __shfl_xor(p, 1, 4);
    p += __shfl_xor(p, 2, 4);
    if (q == 0 && node < N_NODES)
        out[node] = 1.0f / (1.0f + expf(-(p + b3[0])));
}

extern "C" void kernel_launch(void* const* d_in, const int* in_sizes, int n_in,
                              void* d_out, int out_size, void* d_ws, size_t ws_size,
                              hipStream_t stream) {
    const float* feature = (const float*)d_in[0];
    const float* param   = (const float*)d_in[1];
    const float* w1      = (const float*)d_in[2];
    const float* b1      = (const float*)d_in[3];
    const float* w2      = (const float*)d_in[4];
    const float* b2      = (const float*)d_in[5];
    const float* w3      = (const float*)d_in[6];
    const float* b3      = (const float*)d_in[7];
    const int*   src     = (const int*)d_in[8];
    const int*   dst     = (const int*)d_in[9];
    const int*   pid     = (const int*)d_in[10];
    float* out = (float*)d_out;

    const size_t Y_BYTES   = (size_t)N_ET * N_NODES * HD * sizeof(float);   // 51.2 MB
    const size_t NH_BYTES  = (size_t)N_NODES * HD * sizeof(float);          // 6.4 MB
    const size_t DEG_BYTES = (size_t)N_NODES * sizeof(int);                 // 0.2 MB
    char* p = (char*)d_ws;
    float* Y       = (float*)p;            p += Y_BYTES;
    float* cur     = (float*)p;            p += NH_BYTES;
    int*   deg     = (int*)p;              p += DEG_BYTES;
    int*   payload = (int*)p;              // 50K * 64 * 4B = 12.8 MB

    const int TB = 256;
    const int gT = (N_NODES + TB - 1) / TB;          // 196
    const int gE = (N_EDGES + TB - 1) / TB;
    const int gG = (N_NODES * 8 + TB - 1) / TB;      // 1563
    const int gF = (N_NODES * 4 + TB - 1) / TB;      // 782
    dim3 gridT(gT, N_ET);                            // 1568 blocks, t uniform per block

    // Build dst-keyed ELL adjacency (int atomics only, once per launch)
    hipMemsetAsync(deg, 0, DEG_BYTES, stream);
    k_count<<<gE, TB, 0, stream>>>(src, dst, pid, deg, payload);

    // layer 1
    k_transform<<<gridT, TB, 0, stream>>>(feature, param, Y);
    k_gather<<<gG, TB, 0, stream>>>(deg, payload, Y, feature, cur);
    // layer 2
    k_transform<<<gridT, TB, 0, stream>>>(cur, param, Y);
    k_gather<<<gG, TB, 0, stream>>>(deg, payload, Y, cur, cur);
    // layer 3
    k_transform<<<gridT, TB, 0, stream>>>(cur, param, Y);
    k_gather<<<gG, TB, 0, stream>>>(deg, payload, Y, cur, cur);
    // normalize + MLP + sigmoid
    k_final<<<gF, TB, 0, stream>>>(cur, w1, b1, w2, b2, w3, b3, out);
}

// Round 6
// 266.273 us; speedup vs baseline: 3.6123x; 1.2389x over previous
//
#include <hip/hip_runtime.h>
#include <math.h>

#define N_NODES 50000
#define N_EDGES 400000
#define HD 32
#define N_ET 8
#define CAP 64   // ELL capacity; Poisson(8) max degree ~30, P(>=64) ~ 1e-40

__device__ inline void fma4(float4& a, float s, const float4 w) {
    a.x = fmaf(s, w.x, a.x);
    a.y = fmaf(s, w.y, a.y);
    a.z = fmaf(s, w.z, a.z);
    a.w = fmaf(s, w.w, a.w);
}
__device__ inline void add4(float4& a, const float4 v) {
    a.x += v.x; a.y += v.y; a.z += v.z; a.w += v.w;
}

// Build ELL adjacency keyed by dst: payload[d][k] = pid*N_NODES + src
__global__ __launch_bounds__(256) void k_count(
    const int* __restrict__ src, const int* __restrict__ dst,
    const int* __restrict__ pid, int* __restrict__ deg,
    int* __restrict__ payload)
{
    int e = blockIdx.x * blockDim.x + threadIdx.x;
    if (e >= N_EDGES) return;
    int d = dst[e];
    int pos = atomicAdd(&deg[d], 1);
    if (pos < CAP) payload[d * CAP + pos] = pid[e] * N_NODES + src[e];
}

// Transform: Y[t][n] = x[n] @ W_t.  One edge-type per block (blockIdx.y) so the
// weight pointer is wave-uniform -> s_load; one node per thread.
__global__ __launch_bounds__(256) void k_transform(
    const float* __restrict__ xin, const float* __restrict__ param,
    float* __restrict__ Y)
{
    int n = blockIdx.x * blockDim.x + threadIdx.x;
    if (n >= N_NODES) return;
    const int t = blockIdx.y;
    const size_t base = (size_t)n * HD;
    const float* W = param + t * (HD * HD);

    float x[HD];
    #pragma unroll
    for (int q = 0; q < 8; ++q) {
        float4 v = *(const float4*)(xin + base + q * 4);
        x[q * 4 + 0] = v.x; x[q * 4 + 1] = v.y;
        x[q * 4 + 2] = v.z; x[q * 4 + 3] = v.w;
    }

    float4 acc[8];
    #pragma unroll
    for (int q = 0; q < 8; ++q) acc[q] = make_float4(0.f, 0.f, 0.f, 0.f);
    #pragma unroll
    for (int i = 0; i < HD; ++i) {
        float xi = x[i];
        #pragma unroll
        for (int q = 0; q < 8; ++q)
            fma4(acc[q], xi, *(const float4*)(W + i * HD + q * 4));
    }
    float* yo = Y + (size_t)t * N_NODES * HD + base;
    #pragma unroll
    for (int q = 0; q < 8; ++q) *(float4*)(yo + q * 4) = acc[q];
}

// Gather + combine: xout[n] = (xin[n] + sum_{e in in(n)} Y[pid_e][src_e]) * 0.5
// 8 lanes per node; lane sl owns a 16B slice. 4 edges in flight (MLP=4).
__global__ __launch_bounds__(256) void k_gather(
    const int* __restrict__ deg, const int* __restrict__ payload,
    const float* __restrict__ Y, const float* __restrict__ xin,
    float* __restrict__ xout)
{
    int tid = blockIdx.x * blockDim.x + threadIdx.x;
    int node = tid >> 3, sl = tid & 7;
    if (node >= N_NODES) return;
    int d = deg[node];
    if (d > CAP) d = CAP;
    const int* pl = payload + node * CAP;

    float4 a0 = make_float4(0.f,0.f,0.f,0.f), a1 = a0, a2 = a0, a3 = a0;
    int k = 0;
    for (; k + 4 <= d; k += 4) {
        int4 c = *(const int4*)(pl + k);              // 16B aligned (k%4==0)
        float4 v0 = *(const float4*)(Y + (size_t)c.x * HD + sl * 4);
        float4 v1 = *(const float4*)(Y + (size_t)c.y * HD + sl * 4);
        float4 v2 = *(const float4*)(Y + (size_t)c.z * HD + sl * 4);
        float4 v3 = *(const float4*)(Y + (size_t)c.w * HD + sl * 4);
        add4(a0, v0); add4(a1, v1); add4(a2, v2); add4(a3, v3);
    }
    for (; k < d; ++k) {
        int c = pl[k];
        add4(a0, *(const float4*)(Y + (size_t)c * HD + sl * 4));
    }
    add4(a0, a1); add4(a2, a3); add4(a0, a2);

    const size_t off = (size_t)node * HD + sl * 4;
    float4 x = *(const float4*)(xin + off);
    x.x = (x.x + a0.x) * 0.5f;
    x.y = (x.y + a0.y) * 0.5f;
    x.z = (x.z + a0.z) * 0.5f;
    x.w = (x.w + a0.w) * 0.5f;
    *(float4*)(xout + off) = x;
}

// Final: L2-normalize ; MLP 32->64 tanh ->64 tanh ->1 ; sigmoid.
// 8 lanes/node, all-shuffle, no LDS, no barrier. Lane q owns:
//   inputs  x[4q..4q+4)   (one float4)
//   hidden cols [8q,8q+8) (two float4 accumulators) in both layers.
// Broadcasts via __shfl(width 8); outer source-lane loops ROLLED so only a few
// weight loads are in flight -> bounded VGPR (R4/R5 hit the 256-VGPR ceiling).
__global__ __launch_bounds__(256) void k_final(
    const float* __restrict__ cur,
    const float* __restrict__ w1, const float* __restrict__ b1,
    const float* __restrict__ w2, const float* __restrict__ b2,
    const float* __restrict__ w3, const float* __restrict__ b3,
    float* __restrict__ out)
{
    int gt = blockIdx.x * blockDim.x + threadIdx.x;
    int node = gt >> 3, q = gt & 7;
    if (node >= N_NODES) return;                 // whole 8-lane group exits together

    // own slice of x + norm
    float4 xo = *(const float4*)(cur + (size_t)node * HD + q * 4);
    float ss = xo.x * xo.x + xo.y * xo.y + xo.z * xo.z + xo.w * xo.w;
    ss += __shfl_xor(ss, 1, 8);
    ss += __shfl_xor(ss, 2, 8);
    ss += __shfl_xor(ss, 4, 8);
    float rn = 1.0f / fmaxf(sqrtf(ss), 1e-12f);
    xo.x *= rn; xo.y *= rn; xo.z *= rn; xo.w *= rn;

    // layer 1: h = x @ w1 + b1, cols [8q, 8q+8)
    float4 h0 = *(const float4*)(b1 + q * 8);
    float4 h1 = *(const float4*)(b1 + q * 8 + 4);
    for (int s = 0; s < 8; ++s) {                // rolled: bounded live set
        float m0 = __shfl(xo.x, s, 8);
        float m1 = __shfl(xo.y, s, 8);
        float m2 = __shfl(xo.z, s, 8);
        float m3 = __shfl(xo.w, s, 8);
        const float* wr = w1 + (s * 4) * 64 + q * 8;
        fma4(h0, m0, *(const float4*)(wr));
        fma4(h1, m0, *(const float4*)(wr + 4));
        fma4(h0, m1, *(const float4*)(wr + 64));
        fma4(h1, m1, *(const float4*)(wr + 68));
        fma4(h0, m2, *(const float4*)(wr + 128));
        fma4(h1, m2, *(const float4*)(wr + 132));
        fma4(h0, m3, *(const float4*)(wr + 192));
        fma4(h1, m3, *(const float4*)(wr + 196));
    }
    float t1[8];
    t1[0] = tanhf(h0.x); t1[1] = tanhf(h0.y); t1[2] = tanhf(h0.z); t1[3] = tanhf(h0.w);
    t1[4] = tanhf(h1.x); t1[5] = tanhf(h1.y); t1[6] = tanhf(h1.z); t1[7] = tanhf(h1.w);

    // layer 2: h2 = t1 @ w2 + b2, cols [8q, 8q+8)
    float4 g0 = *(const float4*)(b2 + q * 8);
    float4 g1 = *(const float4*)(b2 + q * 8 + 4);
    for (int s = 0; s < 8; ++s) {                // rolled over source lane
        const float* wr = w2 + (s * 8) * 64 + q * 8;
        #pragma unroll
        for (int c = 0; c < 8; ++c) {
            float m = __shfl(t1[c], s, 8);
            fma4(g0, m, *(const float4*)(wr + c * 64));
            fma4(g1, m, *(const float4*)(wr + c * 64 + 4));
        }
    }

    // layer 3: partial dot over own 8 cols, reduce across the 8 lanes
    float4 wa = *(const float4*)(w3 + q * 8);
    float4 wb = *(const float4*)(w3 + q * 8 + 4);
    float p = 0.f;
    p = fmaf(tanhf(g0.x), wa.x, p);
    p = fmaf(tanhf(g0.y), wa.y, p);
    p = fmaf(tanhf(g0.z), wa.z, p);
    p = fmaf(tanhf(g0.w), wa.w, p);
    p = fmaf(tanhf(g1.x), wb.x, p);
    p = fmaf(tanhf(g1.y), wb.y, p);
    p = fmaf(tanhf(g1.z), wb.z, p);
    p = fmaf(tanhf(g1.w), wb.w, p);
    p += __shfl_xor(p, 1, 8);
    p += __shfl_xor(p, 2, 8);
    p += __shfl_xor(p, 4, 8);
    if (q == 0) out[node] = 1.0f / (1.0f + expf(-(p + b3[0])));
}

extern "C" void kernel_launch(void* const* d_in, const int* in_sizes, int n_in,
                              void* d_out, int out_size, void* d_ws, size_t ws_size,
                              hipStream_t stream) {
    const float* feature = (const float*)d_in[0];
    const float* param   = (const float*)d_in[1];
    const float* w1      = (const float*)d_in[2];
    const float* b1      = (const float*)d_in[3];
    const float* w2      = (const float*)d_in[4];
    const float* b2      = (const float*)d_in[5];
    const float* w3      = (const float*)d_in[6];
    const float* b3      = (const float*)d_in[7];
    const int*   src     = (const int*)d_in[8];
    const int*   dst     = (const int*)d_in[9];
    const int*   pid     = (const int*)d_in[10];
    float* out = (float*)d_out;

    const size_t Y_BYTES   = (size_t)N_ET * N_NODES * HD * sizeof(float);   // 51.2 MB
    const size_t NH_BYTES  = (size_t)N_NODES * HD * sizeof(float);          // 6.4 MB
    const size_t DEG_BYTES = (size_t)N_NODES * sizeof(int);                 // 0.2 MB
    char* p = (char*)d_ws;
    float* Y       = (float*)p;            p += Y_BYTES;
    float* cur     = (float*)p;            p += NH_BYTES;
    int*   deg     = (int*)p;              p += DEG_BYTES;
    int*   payload = (int*)p;              // 50K * 64 * 4B = 12.8 MB

    const int TB = 256;
    const int gT = (N_NODES + TB - 1) / TB;          // 196
    const int gE = (N_EDGES + TB - 1) / TB;
    const int gG = (N_NODES * 8 + TB - 1) / TB;      // 1563
    dim3 gridT(gT, N_ET);                            // 1568 blocks, t uniform per block

    // Build dst-keyed ELL adjacency (int atomics only, once per launch)
    hipMemsetAsync(deg, 0, DEG_BYTES, stream);
    k_count<<<gE, TB, 0, stream>>>(src, dst, pid, deg, payload);

    // layer 1
    k_transform<<<gridT, TB, 0, stream>>>(feature, param, Y);
    k_gather<<<gG, TB, 0, stream>>>(deg, payload, Y, feature, cur);
    // layer 2
    k_transform<<<gridT, TB, 0, stream>>>(cur, param, Y);
    k_gather<<<gG, TB, 0, stream>>>(deg, payload, Y, cur, cur);
    // layer 3
    k_transform<<<gridT, TB, 0, stream>>>(cur, param, Y);
    k_gather<<<gG, TB, 0, stream>>>(deg, payload, Y, cur, cur);
    // normalize + MLP + sigmoid
    k_final<<<gG, TB, 0, stream>>>(cur, w1, b1, w2, b2, w3, b3, out);
}